// Round 16
// baseline (300.760 us; speedup 1.0000x reference)
//
#include <hip/hip_runtime.h>
#include <cstdint>
#include <cstddef>

#define NCLS 5

typedef unsigned short ushort_t;
typedef __attribute__((ext_vector_type(8))) short short8v;   // 8 bf16 (4 VGPRs)
typedef __attribute__((ext_vector_type(4))) float f32x4;     // MFMA accumulator

__device__ __forceinline__ float sigf(float x) { return 1.0f / (1.0f + __expf(-x)); }

__device__ __forceinline__ unsigned short bf16_rne(float x) {
    unsigned u = __float_as_uint(x);
    u += 0x7FFFu + ((u >> 16) & 1u);
    return (unsigned short)(u >> 16);
}
__device__ __forceinline__ float bf16_f32(unsigned short h) {
    return __uint_as_float(((unsigned)h) << 16);
}

__device__ __forceinline__ void cvt_hilo(float4 f0, float4 f1, short8v& hi, short8v& lo) {
    float v[8] = { f0.x, f0.y, f0.z, f0.w, f1.x, f1.y, f1.z, f1.w };
#pragma unroll
    for (int e = 0; e < 8; ++e) {
        unsigned short h = bf16_rne(v[e]);
        unsigned short l = bf16_rne(v[e] - bf16_f32(h));
        hi[e] = (short)h; lo[e] = (short)l;
    }
}

// ---------------------------------------------------------------------------
// Weight prep (fragment-ordered, f1/f2 packed — verified).
// Level WtPL[cb 8][cc 16][slot 4][lane 64][e 8]:
//   band=cc>>3 (hi/lo), c8=cc&7, csel=c8>>2, kc=(c8&3)*32+kq, kq=(lane>>4)*8+e
//   slot 0..2 = Ui/Uo/Uu at K=csel*128+kc; slot 3 = csel? Uf2[kc] : Uf1[kc]
// Leaf WtPF[cb 8][cc 8][slot 3][lane][e]: band=cc>>2, kc=(cc&3)*32+kq
// ---------------------------------------------------------------------------
__global__ __launch_bounds__(256)
void prep_w(const float* __restrict__ Wi, const float* __restrict__ Wo,
            const float* __restrict__ Wu,
            const float* __restrict__ Ui, const float* __restrict__ Uo,
            const float* __restrict__ Uu, const float* __restrict__ Uf1,
            const float* __restrict__ Uf2,
            ushort_t* __restrict__ WtPL, ushort_t* __restrict__ WtPF)
{
    int b = blockIdx.x;
    if (b < 1024) {
        int idx = b * 256 + threadIdx.x;              // 262144
        int e = idx & 7, lane = (idx >> 3) & 63;
        int slot = (idx >> 9) & 3, cc = (idx >> 11) & 15, cb = idx >> 15;
        int j  = cb * 16 + (lane & 15);
        int kq = (lane >> 4) * 8 + e;
        int band = cc >> 3, c8 = cc & 7, csel = c8 >> 2;
        int kc = (c8 & 3) * 32 + kq;                  // [0,128)
        float x;
        if      (slot == 0) x = Ui[(csel * 128 + kc) * 128 + j];
        else if (slot == 1) x = Uo[(csel * 128 + kc) * 128 + j];
        else if (slot == 2) x = Uu[(csel * 128 + kc) * 128 + j];
        else                x = csel ? Uf2[kc * 128 + j] : Uf1[kc * 128 + j];
        unsigned short h = bf16_rne(x);
        if (band) h = bf16_rne(x - bf16_f32(h));
        WtPL[idx] = h;
    } else {
        int idx = (b - 1024) * 256 + threadIdx.x;     // 98304
        if (idx >= 98304) return;
        int e = idx & 7, lane = (idx >> 3) & 63;
        int rest = idx >> 9;
        int slot = rest % 3, cc = (rest / 3) & 7, cb = rest / 24;
        int j  = cb * 16 + (lane & 15);
        int kq = (lane >> 4) * 8 + e;
        int band = cc >> 2;
        int kc = (cc & 3) * 32 + kq;                  // [0,128)
        const float* W = (slot == 0) ? Wi : (slot == 1) ? Wo : Wu;
        float x = W[kc * 128 + j];
        unsigned short h = bf16_rne(x);
        if (band) h = bf16_rne(x - bf16_f32(h));
        WtPF[idx] = h;
    }
}

// ---------------------------------------------------------------------------
// Leaf (BM=64, RT=4): gather+convert once per block into LDS (64 rows), then
// 8 waves compute; each wave owns a 16-col j-block and 4 row-tiles.
// B traffic per block: 192 KB for 64 rows (was 32) -> half the L3 feed.
// ---------------------------------------------------------------------------
__global__ __launch_bounds__(512)
void leaf_stream(const int* __restrict__ words, const float* __restrict__ emb,
                 const ushort_t* __restrict__ WtPF,
                 const float* __restrict__ bi, const float* __restrict__ bo,
                 const float* __restrict__ bu,
                 ushort_t* __restrict__ H2out, ushort_t* __restrict__ C2out)
{
    __shared__ ushort_t EA[64 * 264];                 // 33 KB
    const int tid = threadIdx.x, lane = tid & 63, wc = tid >> 6;
    const int l15 = lane & 15, l4 = lane >> 4;
    const int rb = blockIdx.x * 64;
    const ushort_t* slab = WtPF + (size_t)wc * 12288;

    // ---- convert phase: 1024 (row,group) items over 512 threads ----
#pragma unroll
    for (int it = 0; it < 2; ++it) {
        const int idx = tid + it * 512;               // [0,1024)
        const int rl = idx >> 4;                      // [0,64)
        const int g  = idx & 15;
        const float* e = emb + (size_t)words[rb + rl] * 128 + g * 8;
        float4 f0 = *(const float4*)(e);
        float4 f1 = *(const float4*)(e + 4);
        short8v hi, lo;
        cvt_hilo(f0, f1, hi, lo);
        *(short8v*)(EA + rl * 264 + g * 8)       = hi;
        *(short8v*)(EA + rl * 264 + 128 + g * 8) = lo;
    }
    __syncthreads();

    f32x4 acc[4][3];
#pragma unroll
    for (int rt = 0; rt < 4; ++rt)
#pragma unroll
        for (int g = 0; g < 3; ++g) acc[rt][g] = (f32x4){0.f, 0.f, 0.f, 0.f};

#pragma unroll
    for (int cc = 0; cc < 4; ++cc) {
        const int ko = cc * 32 + l4 * 8;
        short8v Ah[4], Al[4];
#pragma unroll
        for (int rt = 0; rt < 4; ++rt) {
            Ah[rt] = *(const short8v*)(EA + (rt * 16 + l15) * 264 + ko);
            Al[rt] = *(const short8v*)(EA + (rt * 16 + l15) * 264 + 128 + ko);
        }
        short8v Bh[3], Bl[3];
#pragma unroll
        for (int s = 0; s < 3; ++s) {
            Bh[s] = *(const short8v*)(slab + (size_t)(cc * 3 + s) * 512 + lane * 8);
            Bl[s] = *(const short8v*)(slab + (size_t)((cc + 4) * 3 + s) * 512 + lane * 8);
        }
#pragma unroll
        for (int s = 0; s < 3; ++s)
#pragma unroll
            for (int rt = 0; rt < 4; ++rt) {
                acc[rt][s] = __builtin_amdgcn_mfma_f32_16x16x32_bf16(Ah[rt], Bh[s], acc[rt][s], 0, 0, 0);
                acc[rt][s] = __builtin_amdgcn_mfma_f32_16x16x32_bf16(Al[rt], Bh[s], acc[rt][s], 0, 0, 0);
                acc[rt][s] = __builtin_amdgcn_mfma_f32_16x16x32_bf16(Ah[rt], Bl[s], acc[rt][s], 0, 0, 0);
            }
    }

    const int j = wc * 16 + l15;
    const float bi_ = bi[j], bo_ = bo[j], bu_ = bu[j];
#pragma unroll
    for (int rt = 0; rt < 4; ++rt)
#pragma unroll
        for (int v = 0; v < 4; ++v) {
            const int row = rb + rt * 16 + l4 * 4 + v;
            float iv = sigf(acc[rt][0][v] + bi_);
            float ov = sigf(acc[rt][1][v] + bo_);
            float uv = fmaxf(acc[rt][2][v] + bu_, 0.f);
            float c_ = iv * uv;
            float h_ = ov * fmaxf(c_, 0.f);
            unsigned short chi = bf16_rne(c_);
            unsigned short clo = bf16_rne(c_ - bf16_f32(chi));
            unsigned short hhi = bf16_rne(h_);
            unsigned short hlo = bf16_rne(h_ - bf16_f32(hhi));
            C2out[(size_t)row * 256 + j]       = chi;
            C2out[(size_t)row * 256 + 128 + j] = clo;
            H2out[(size_t)row * 256 + j]       = hhi;
            H2out[(size_t)row * 256 + 128 + j] = hlo;
        }
}

// ---------------------------------------------------------------------------
// Level stream (m >= 8192): BM=16*RT, 8 waves, compiler-scheduled loads.
// RT=4 halves the dominant per-block B re-read vs RT=2.
// ---------------------------------------------------------------------------
template<int RT>
__global__ __launch_bounds__(512)
void level_stream(const ushort_t* __restrict__ H2in, const ushort_t* __restrict__ C2in,
                  const ushort_t* __restrict__ WtPL,
                  const float* __restrict__ bUi, const float* __restrict__ bUo,
                  const float* __restrict__ bUu, const float* __restrict__ bf1,
                  const float* __restrict__ bf2,
                  ushort_t* __restrict__ H2out, ushort_t* __restrict__ C2out)
{
    const int tid = threadIdx.x, lane = tid & 63, wc = tid >> 6;
    const int l15 = lane & 15, l4 = lane >> 4;
    const int rb = blockIdx.x * (16 * RT);
    const ushort_t* slab = WtPL + (size_t)wc * 32768;

    const ushort_t* r[RT];
#pragma unroll
    for (int rt = 0; rt < RT; ++rt)
        r[rt] = H2in + (size_t)(2 * (rb + rt * 16 + l15)) * 256;

    f32x4 acc[RT][5];
#pragma unroll
    for (int rt = 0; rt < RT; ++rt)
#pragma unroll
        for (int g = 0; g < 5; ++g) acc[rt][g] = (f32x4){0.f, 0.f, 0.f, 0.f};

#pragma unroll
    for (int cc = 0; cc < 8; ++cc) {
        const int csel = cc >> 2;
        const int aoff = csel * 256 + (cc & 3) * 32 + l4 * 8;
        short8v Ah[RT], Al[RT];
#pragma unroll
        for (int rt = 0; rt < RT; ++rt) {
            Ah[rt] = *(const short8v*)(r[rt] + aoff);
            Al[rt] = *(const short8v*)(r[rt] + aoff + 128);
        }
        short8v Bh[4], Bw[4];
#pragma unroll
        for (int s = 0; s < 4; ++s) {
            Bh[s] = *(const short8v*)(slab + (size_t)(cc * 4 + s) * 512 + lane * 8);
            Bw[s] = *(const short8v*)(slab + (size_t)((cc + 8) * 4 + s) * 512 + lane * 8);
        }
#pragma unroll
        for (int s = 0; s < 4; ++s) {
            const int col = (s < 3) ? s : 3 + csel;
#pragma unroll
            for (int rt = 0; rt < RT; ++rt) {
                acc[rt][col] = __builtin_amdgcn_mfma_f32_16x16x32_bf16(Ah[rt], Bh[s], acc[rt][col], 0, 0, 0);
                acc[rt][col] = __builtin_amdgcn_mfma_f32_16x16x32_bf16(Al[rt], Bh[s], acc[rt][col], 0, 0, 0);
                acc[rt][col] = __builtin_amdgcn_mfma_f32_16x16x32_bf16(Ah[rt], Bw[s], acc[rt][col], 0, 0, 0);
            }
        }
    }

    const int j = wc * 16 + l15;
    const float b0_ = bUi[j], b1_ = bUo[j], b2_ = bUu[j], b3_ = bf1[j], b4_ = bf2[j];
#pragma unroll
    for (int rt = 0; rt < RT; ++rt)
#pragma unroll
        for (int v = 0; v < 4; ++v) {
            const int row = rb + rt * 16 + l4 * 4 + v;
            float iv  = sigf(acc[rt][0][v] + b0_);
            float ov  = sigf(acc[rt][1][v] + b1_);
            float uv  = fmaxf(acc[rt][2][v] + b2_, 0.f);
            float f1v = sigf(acc[rt][3][v] + b3_);
            float f2v = sigf(acc[rt][4][v] + b4_);
            const ushort_t* cl = C2in + (size_t)(2 * row) * 256;
            float lC = bf16_f32(cl[j])       + bf16_f32(cl[128 + j]);
            float rC = bf16_f32(cl[256 + j]) + bf16_f32(cl[384 + j]);
            float c_ = fmaf(iv, uv, fmaf(f1v, lC, f2v * rC));
            float h_ = ov * fmaxf(c_, 0.f);
            unsigned short chi = bf16_rne(c_);
            unsigned short clo = bf16_rne(c_ - bf16_f32(chi));
            unsigned short hhi = bf16_rne(h_);
            unsigned short hlo = bf16_rne(h_ - bf16_f32(hhi));
            C2out[(size_t)row * 256 + j]       = chi;
            C2out[(size_t)row * 256 + 128 + j] = clo;
            H2out[(size_t)row * 256 + j]       = hhi;
            H2out[(size_t)row * 256 + 128 + j] = hlo;
        }
}

// ---------------------------------------------------------------------------
// Tiny level (m <= 4096): 1 wave per block; grid (ceil(m/16), 8),
// cb = blockIdx.y. Proven ~4.3 µs/launch. (unchanged)
// ---------------------------------------------------------------------------
__global__ __launch_bounds__(64)
void level_tiny(const ushort_t* __restrict__ H2in, const ushort_t* __restrict__ C2in,
                const ushort_t* __restrict__ WtPL,
                const float* __restrict__ bUi, const float* __restrict__ bUo,
                const float* __restrict__ bUu, const float* __restrict__ bf1,
                const float* __restrict__ bf2,
                ushort_t* __restrict__ H2out, ushort_t* __restrict__ C2out, int n)
{
    const int lane = threadIdx.x;
    const int l15 = lane & 15, l4 = lane >> 4;
    const int cb = blockIdx.y;
    const int rb = blockIdx.x * 16;
    const ushort_t* slab = WtPL + (size_t)cb * 32768;

    int prow = rb + l15; if (prow > n - 1) prow = n - 1;
    const ushort_t* r0 = H2in + (size_t)(2 * prow) * 256;

    f32x4 acc[5];
#pragma unroll
    for (int g = 0; g < 5; ++g) acc[g] = (f32x4){0.f, 0.f, 0.f, 0.f};

#pragma unroll
    for (int cc = 0; cc < 8; ++cc) {
        const int csel = cc >> 2;
        const int aoff = csel * 256 + (cc & 3) * 32 + l4 * 8;
        short8v Ah = *(const short8v*)(r0 + aoff);
        short8v Al = *(const short8v*)(r0 + aoff + 128);
#pragma unroll
        for (int s = 0; s < 4; ++s) {
            const int col = (s < 3) ? s : 3 + csel;
            short8v Bh = *(const short8v*)(slab + (size_t)(cc * 4 + s) * 512 + lane * 8);
            short8v Bw = *(const short8v*)(slab + (size_t)((cc + 8) * 4 + s) * 512 + lane * 8);
            acc[col] = __builtin_amdgcn_mfma_f32_16x16x32_bf16(Ah, Bh, acc[col], 0, 0, 0);
            acc[col] = __builtin_amdgcn_mfma_f32_16x16x32_bf16(Al, Bh, acc[col], 0, 0, 0);
            acc[col] = __builtin_amdgcn_mfma_f32_16x16x32_bf16(Ah, Bw, acc[col], 0, 0, 0);
        }
    }

    const int j = cb * 16 + l15;
    const float b0_ = bUi[j], b1_ = bUo[j], b2_ = bUu[j], b3_ = bf1[j], b4_ = bf2[j];
#pragma unroll
    for (int v = 0; v < 4; ++v) {
        const int row = rb + l4 * 4 + v;
        if (row < n) {
            float iv  = sigf(acc[0][v] + b0_);
            float ov  = sigf(acc[1][v] + b1_);
            float uv  = fmaxf(acc[2][v] + b2_, 0.f);
            float f1v = sigf(acc[3][v] + b3_);
            float f2v = sigf(acc[4][v] + b4_);
            const ushort_t* cl = C2in + (size_t)(2 * row) * 256;
            float lC = bf16_f32(cl[j])       + bf16_f32(cl[128 + j]);
            float rC = bf16_f32(cl[256 + j]) + bf16_f32(cl[384 + j]);
            float c_ = fmaf(iv, uv, fmaf(f1v, lC, f2v * rC));
            float h_ = ov * fmaxf(c_, 0.f);
            unsigned short chi = bf16_rne(c_);
            unsigned short clo = bf16_rne(c_ - bf16_f32(chi));
            unsigned short hhi = bf16_rne(h_);
            unsigned short hlo = bf16_rne(h_ - bf16_f32(hhi));
            C2out[(size_t)row * 256 + j]       = chi;
            C2out[(size_t)row * 256 + 128 + j] = clo;
            H2out[(size_t)row * 256 + j]       = hhi;
            H2out[(size_t)row * 256 + 128 + j] = hlo;
        }
    }
}

// ---------------------------------------------------------------------------
// Projection: 4 rows per wave, P cached in registers. (unchanged)
// ---------------------------------------------------------------------------
__global__ __launch_bounds__(256)
void proj4(const ushort_t* __restrict__ H2, const float* __restrict__ P,
           const float* __restrict__ bP, float* __restrict__ out, int total)
{
    const int w = blockIdx.x * 4 + (threadIdx.x >> 6);
    const int lane = threadIdx.x & 63;
    const int k0 = 2 * lane, k1 = 2 * lane + 1;
    float p0[NCLS], p1[NCLS];
#pragma unroll
    for (int c = 0; c < NCLS; ++c) { p0[c] = P[k0 * NCLS + c]; p1[c] = P[k1 * NCLS + c]; }

    for (int rr = 0; rr < 4; ++rr) {
        const int row = w * 4 + rr;
        if (row >= total) return;
        const unsigned* hr = (const unsigned*)(H2 + (size_t)row * 256);
        unsigned uh = hr[lane];
        unsigned ul = hr[64 + lane];
        float h0 = bf16_f32((unsigned short)(uh & 0xffffu)) + bf16_f32((unsigned short)(ul & 0xffffu));
        float h1 = bf16_f32((unsigned short)(uh >> 16)) + bf16_f32((unsigned short)(ul >> 16));
        float a[NCLS];
#pragma unroll
        for (int c = 0; c < NCLS; ++c)
            a[c] = fmaf(h0, p0[c], h1 * p1[c]);
        for (int off = 32; off; off >>= 1)
#pragma unroll
            for (int c = 0; c < NCLS; ++c) a[c] += __shfl_down(a[c], off, 64);
        if (lane == 0)
#pragma unroll
            for (int c = 0; c < NCLS; ++c) out[(size_t)row * NCLS + c] = a[c] + bP[c];
    }
}

// ---------------------------------------------------------------------------
// Host launcher.
// ws: WtPL@0 (512K) | WtPF@524288 (192K) | H2@1048576 (67.11M) | C2@68157440
// (67.11M) — ends ~135.3 MB. Node rows write-once; offsets: leaf@0,
// 32768@65536, 16384@98304, 8192@114688, then tiny levels 4096..1 appended.
// ---------------------------------------------------------------------------
extern "C" void kernel_launch(void* const* d_in, const int* in_sizes, int n_in,
                              void* d_out, int out_size, void* d_ws, size_t ws_size,
                              hipStream_t stream)
{
    const int*   words = (const int*)  d_in[0];
    const float* emb   = (const float*)d_in[1];
    const float* Wi  = (const float*)d_in[2];  const float* bi  = (const float*)d_in[3];
    const float* Wo  = (const float*)d_in[4];  const float* bo  = (const float*)d_in[5];
    const float* Wu  = (const float*)d_in[6];  const float* bu  = (const float*)d_in[7];
    const float* Ui  = (const float*)d_in[8];  const float* bUi = (const float*)d_in[9];
    const float* Uo  = (const float*)d_in[10]; const float* bUo = (const float*)d_in[11];
    const float* Uu  = (const float*)d_in[12]; const float* bUu = (const float*)d_in[13];
    const float* Uf1 = (const float*)d_in[14]; const float* bf1 = (const float*)d_in[15];
    const float* Uf2 = (const float*)d_in[16]; const float* bf2 = (const float*)d_in[17];
    const float* Pm  = (const float*)d_in[18]; const float* bP  = (const float*)d_in[19];
    float* out = (float*)d_out;

    ushort_t* WtPL = (ushort_t*)d_ws;
    ushort_t* WtPF = (ushort_t*)((char*)d_ws + 524288);
    ushort_t* H2   = (ushort_t*)((char*)d_ws + 1048576);
    ushort_t* C2   = (ushort_t*)((char*)d_ws + 68157440);

    prep_w<<<1408, 256, 0, stream>>>(Wi, Wo, Wu, Ui, Uo, Uu, Uf1, Uf2, WtPL, WtPF);

    leaf_stream<<<1024, 512, 0, stream>>>(words, emb, WtPF, bi, bo, bu, H2, C2);

    // big levels: m = 32768, 16384, 8192 (BM=64, RT=4)
    int off_prev = 0, off = 65536, m = 32768;
    while (m >= 8192) {
        level_stream<4><<<m / 64, 512, 0, stream>>>(
            H2 + (size_t)off_prev * 256, C2 + (size_t)off_prev * 256, WtPL,
            bUi, bUo, bUu, bf1, bf2,
            H2 + (size_t)off * 256, C2 + (size_t)off * 256);
        off_prev = off; off += m; m >>= 1;
    }

    // tail: m = 4096 .. 1, one tiny launch each (proven ~4.3 µs/launch)
    while (m >= 1) {
        level_tiny<<<dim3((m + 15) / 16, 8), 64, 0, stream>>>(
            H2 + (size_t)off_prev * 256, C2 + (size_t)off_prev * 256, WtPL,
            bUi, bUo, bUu, bf1, bf2,
            H2 + (size_t)off * 256, C2 + (size_t)off * 256, m);
        off_prev = off; off += m; m >>= 1;
    }

    proj4<<<8192, 256, 0, stream>>>(H2, Pm, bP, out, 131071);
}

// Round 17
// 244.914 us; speedup vs baseline: 1.2280x; 1.2280x over previous
//
#include <hip/hip_runtime.h>
#include <cstdint>
#include <cstddef>

#define NCLS 5

typedef unsigned short ushort_t;
typedef __attribute__((ext_vector_type(8))) short short8v;   // 8 bf16 (4 VGPRs)
typedef __attribute__((ext_vector_type(4))) float f32x4;     // MFMA accumulator

__device__ __forceinline__ float sigf(float x) { return 1.0f / (1.0f + __expf(-x)); }

__device__ __forceinline__ unsigned short bf16_rne(float x) {
    unsigned u = __float_as_uint(x);
    u += 0x7FFFu + ((u >> 16) & 1u);
    return (unsigned short)(u >> 16);
}
__device__ __forceinline__ float bf16_f32(unsigned short h) {
    return __uint_as_float(((unsigned)h) << 16);
}

__device__ __forceinline__ void cvt_hilo(float4 f0, float4 f1, short8v& hi, short8v& lo) {
    float v[8] = { f0.x, f0.y, f0.z, f0.w, f1.x, f1.y, f1.z, f1.w };
#pragma unroll
    for (int e = 0; e < 8; ++e) {
        unsigned short h = bf16_rne(v[e]);
        unsigned short l = bf16_rne(v[e] - bf16_f32(h));
        hi[e] = (short)h; lo[e] = (short)l;
    }
}

// ---------------------------------------------------------------------------
// Weight prep (fragment-ordered, f1/f2 packed — verified).
// Level WtPL[cb 8][cc 16][slot 4][lane 64][e 8]:
//   band=cc>>3 (hi/lo), c8=cc&7, csel=c8>>2, kc=(c8&3)*32+kq, kq=(lane>>4)*8+e
//   slot 0..2 = Ui/Uo/Uu at K=csel*128+kc; slot 3 = csel? Uf2[kc] : Uf1[kc]
// Leaf WtPF[cb 8][cc 8][slot 3][lane][e]: band=cc>>2, kc=(cc&3)*32+kq
// ---------------------------------------------------------------------------
__global__ __launch_bounds__(256)
void prep_w(const float* __restrict__ Wi, const float* __restrict__ Wo,
            const float* __restrict__ Wu,
            const float* __restrict__ Ui, const float* __restrict__ Uo,
            const float* __restrict__ Uu, const float* __restrict__ Uf1,
            const float* __restrict__ Uf2,
            ushort_t* __restrict__ WtPL, ushort_t* __restrict__ WtPF)
{
    int b = blockIdx.x;
    if (b < 1024) {
        int idx = b * 256 + threadIdx.x;              // 262144
        int e = idx & 7, lane = (idx >> 3) & 63;
        int slot = (idx >> 9) & 3, cc = (idx >> 11) & 15, cb = idx >> 15;
        int j  = cb * 16 + (lane & 15);
        int kq = (lane >> 4) * 8 + e;
        int band = cc >> 3, c8 = cc & 7, csel = c8 >> 2;
        int kc = (c8 & 3) * 32 + kq;                  // [0,128)
        float x;
        if      (slot == 0) x = Ui[(csel * 128 + kc) * 128 + j];
        else if (slot == 1) x = Uo[(csel * 128 + kc) * 128 + j];
        else if (slot == 2) x = Uu[(csel * 128 + kc) * 128 + j];
        else                x = csel ? Uf2[kc * 128 + j] : Uf1[kc * 128 + j];
        unsigned short h = bf16_rne(x);
        if (band) h = bf16_rne(x - bf16_f32(h));
        WtPL[idx] = h;
    } else {
        int idx = (b - 1024) * 256 + threadIdx.x;     // 98304
        if (idx >= 98304) return;
        int e = idx & 7, lane = (idx >> 3) & 63;
        int rest = idx >> 9;
        int slot = rest % 3, cc = (rest / 3) & 7, cb = rest / 24;
        int j  = cb * 16 + (lane & 15);
        int kq = (lane >> 4) * 8 + e;
        int band = cc >> 2;
        int kc = (cc & 3) * 32 + kq;                  // [0,128)
        const float* W = (slot == 0) ? Wi : (slot == 1) ? Wo : Wu;
        float x = W[kc * 128 + j];
        unsigned short h = bf16_rne(x);
        if (band) h = bf16_rne(x - bf16_f32(h));
        WtPF[idx] = h;
    }
}

// ---------------------------------------------------------------------------
// Leaf: gather+convert ONCE per block into LDS (each wave does 4 rows), then
// all 8 waves read A-frags from LDS; B depth-1 prefetched. BM=32.
// (byte-identical to the 275 µs round-14 version)
// ---------------------------------------------------------------------------
__global__ __launch_bounds__(512)
void leaf_stream(const int* __restrict__ words, const float* __restrict__ emb,
                 const ushort_t* __restrict__ WtPF,
                 const float* __restrict__ bi, const float* __restrict__ bo,
                 const float* __restrict__ bu,
                 ushort_t* __restrict__ H2out, ushort_t* __restrict__ C2out)
{
    __shared__ ushort_t EA[32 * 264];                 // 16.5 KB
    const int tid = threadIdx.x, lane = tid & 63, wc = tid >> 6;
    const int l15 = lane & 15, l4 = lane >> 4;
    const int rb = blockIdx.x * 32;
    const ushort_t* slab = WtPF + (size_t)wc * 12288;

    {
        const int rl = wc * 4 + (lane >> 4);          // [0,32)
        const int g  = lane & 15;
        const float* e = emb + (size_t)words[rb + rl] * 128 + g * 8;
        float4 f0 = *(const float4*)(e);
        float4 f1 = *(const float4*)(e + 4);
        short8v hi, lo;
        cvt_hilo(f0, f1, hi, lo);
        *(short8v*)(EA + rl * 264 + g * 8)       = hi;
        *(short8v*)(EA + rl * 264 + 128 + g * 8) = lo;
    }
    __syncthreads();

    f32x4 acc[2][3];
#pragma unroll
    for (int fr = 0; fr < 2; ++fr)
#pragma unroll
        for (int g = 0; g < 3; ++g) acc[fr][g] = (f32x4){0.f, 0.f, 0.f, 0.f};

    short8v pB0, pB1, pB2, pB3, pB4, pB5;
#define LEAF_B(c) do {                                                        \
        pB0 = *(const short8v*)(slab + (size_t)((c) * 3 + 0) * 512 + lane * 8); \
        pB1 = *(const short8v*)(slab + (size_t)((c) * 3 + 1) * 512 + lane * 8); \
        pB2 = *(const short8v*)(slab + (size_t)((c) * 3 + 2) * 512 + lane * 8); \
        pB3 = *(const short8v*)(slab + (size_t)(((c) + 4) * 3 + 0) * 512 + lane * 8); \
        pB4 = *(const short8v*)(slab + (size_t)(((c) + 4) * 3 + 1) * 512 + lane * 8); \
        pB5 = *(const short8v*)(slab + (size_t)(((c) + 4) * 3 + 2) * 512 + lane * 8); \
    } while (0)

    LEAF_B(0);
#pragma unroll
    for (int cc = 0; cc < 4; ++cc) {
        short8v Bh[3] = { pB0, pB1, pB2 };
        short8v Bl[3] = { pB3, pB4, pB5 };
        if (cc < 3) LEAF_B(cc + 1);
        const int ko = cc * 32 + l4 * 8;
        short8v Ah0 = *(const short8v*)(EA + l15 * 264 + ko);
        short8v Ah1 = *(const short8v*)(EA + (16 + l15) * 264 + ko);
        short8v Al0 = *(const short8v*)(EA + l15 * 264 + 128 + ko);
        short8v Al1 = *(const short8v*)(EA + (16 + l15) * 264 + 128 + ko);
#pragma unroll
        for (int s = 0; s < 3; ++s) {
            acc[0][s] = __builtin_amdgcn_mfma_f32_16x16x32_bf16(Ah0, Bh[s], acc[0][s], 0, 0, 0);
            acc[1][s] = __builtin_amdgcn_mfma_f32_16x16x32_bf16(Ah1, Bh[s], acc[1][s], 0, 0, 0);
            acc[0][s] = __builtin_amdgcn_mfma_f32_16x16x32_bf16(Al0, Bh[s], acc[0][s], 0, 0, 0);
            acc[1][s] = __builtin_amdgcn_mfma_f32_16x16x32_bf16(Al1, Bh[s], acc[1][s], 0, 0, 0);
            acc[0][s] = __builtin_amdgcn_mfma_f32_16x16x32_bf16(Ah0, Bl[s], acc[0][s], 0, 0, 0);
            acc[1][s] = __builtin_amdgcn_mfma_f32_16x16x32_bf16(Ah1, Bl[s], acc[1][s], 0, 0, 0);
        }
    }
#undef LEAF_B

    const int j = wc * 16 + l15;
    const float bi_ = bi[j], bo_ = bo[j], bu_ = bu[j];
#pragma unroll
    for (int fr = 0; fr < 2; ++fr)
#pragma unroll
        for (int v = 0; v < 4; ++v) {
            const int row = rb + fr * 16 + l4 * 4 + v;
            float iv = sigf(acc[fr][0][v] + bi_);
            float ov = sigf(acc[fr][1][v] + bo_);
            float uv = fmaxf(acc[fr][2][v] + bu_, 0.f);
            float c_ = iv * uv;
            float h_ = ov * fmaxf(c_, 0.f);
            unsigned short chi = bf16_rne(c_);
            unsigned short clo = bf16_rne(c_ - bf16_f32(chi));
            unsigned short hhi = bf16_rne(h_);
            unsigned short hlo = bf16_rne(h_ - bf16_f32(hhi));
            C2out[(size_t)row * 256 + j]       = chi;
            C2out[(size_t)row * 256 + 128 + j] = clo;
            H2out[(size_t)row * 256 + j]       = hhi;
            H2out[(size_t)row * 256 + 128 + j] = hlo;
        }
}

// ---------------------------------------------------------------------------
// Level with LDS-staged A (m >= 8192). BM=32, 8 waves.
// Stage the 64 child rows (32 KB, contiguous in H2) into LDS once, fully
// coalesced (64B/thread); one barrier; A-frags then come from LDS, killing
// the 8x-redundant 16-line-scattered global A reads. B stays global (L2-hot).
// LDS 33.8 KB -> 2+ blocks/CU.
// ---------------------------------------------------------------------------
__global__ __launch_bounds__(512)
void level_lds(const ushort_t* __restrict__ H2in, const ushort_t* __restrict__ C2in,
               const ushort_t* __restrict__ WtPL,
               const float* __restrict__ bUi, const float* __restrict__ bUo,
               const float* __restrict__ bUu, const float* __restrict__ bf1,
               const float* __restrict__ bf2,
               ushort_t* __restrict__ H2out, ushort_t* __restrict__ C2out)
{
    __shared__ ushort_t EA[64 * 264];                 // 33.8 KB
    const int tid = threadIdx.x, lane = tid & 63, wc = tid >> 6;
    const int l15 = lane & 15, l4 = lane >> 4;
    const int rb = blockIdx.x * 32;
    const ushort_t* slab = WtPL + (size_t)wc * 32768;

    // ---- stage 64 child rows: contiguous 32 KB from H2in + 2*rb*256 ----
    {
        const ushort_t* src = H2in + (size_t)(2 * rb) * 256;
        const int cr  = tid >> 3;                     // [0,64) child row
        const int seg = tid & 7;                      // 64B segment
#pragma unroll
        for (int i = 0; i < 4; ++i) {
            short8v v = *(const short8v*)(src + cr * 256 + seg * 32 + i * 8);
            *(short8v*)(EA + cr * 264 + seg * 32 + i * 8) = v;
        }
    }
    __syncthreads();

    f32x4 acc[2][5];
#pragma unroll
    for (int fr = 0; fr < 2; ++fr)
#pragma unroll
        for (int g = 0; g < 5; ++g) acc[fr][g] = (f32x4){0.f, 0.f, 0.f, 0.f};

#pragma unroll
    for (int cc = 0; cc < 8; ++cc) {
        const int csel = cc >> 2;
        const int ko = (cc & 3) * 32 + l4 * 8;
        short8v Ah0 = *(const short8v*)(EA + (2 * l15 + csel) * 264 + ko);
        short8v Ah1 = *(const short8v*)(EA + (2 * (16 + l15) + csel) * 264 + ko);
        short8v Al0 = *(const short8v*)(EA + (2 * l15 + csel) * 264 + 128 + ko);
        short8v Al1 = *(const short8v*)(EA + (2 * (16 + l15) + csel) * 264 + 128 + ko);
        short8v Bh[4], Bw[4];
#pragma unroll
        for (int s = 0; s < 4; ++s) {
            Bh[s] = *(const short8v*)(slab + (size_t)(cc * 4 + s) * 512 + lane * 8);
            Bw[s] = *(const short8v*)(slab + (size_t)((cc + 8) * 4 + s) * 512 + lane * 8);
        }
#pragma unroll
        for (int s = 0; s < 4; ++s) {
            const int col = (s < 3) ? s : 3 + csel;
            acc[0][col] = __builtin_amdgcn_mfma_f32_16x16x32_bf16(Ah0, Bh[s], acc[0][col], 0, 0, 0);
            acc[1][col] = __builtin_amdgcn_mfma_f32_16x16x32_bf16(Ah1, Bh[s], acc[1][col], 0, 0, 0);
            acc[0][col] = __builtin_amdgcn_mfma_f32_16x16x32_bf16(Al0, Bh[s], acc[0][col], 0, 0, 0);
            acc[1][col] = __builtin_amdgcn_mfma_f32_16x16x32_bf16(Al1, Bh[s], acc[1][col], 0, 0, 0);
            acc[0][col] = __builtin_amdgcn_mfma_f32_16x16x32_bf16(Ah0, Bw[s], acc[0][col], 0, 0, 0);
            acc[1][col] = __builtin_amdgcn_mfma_f32_16x16x32_bf16(Ah1, Bw[s], acc[1][col], 0, 0, 0);
        }
    }

    const int j = wc * 16 + l15;
    const float b0_ = bUi[j], b1_ = bUo[j], b2_ = bUu[j], b3_ = bf1[j], b4_ = bf2[j];
#pragma unroll
    for (int fr = 0; fr < 2; ++fr)
#pragma unroll
        for (int v = 0; v < 4; ++v) {
            const int row = rb + fr * 16 + l4 * 4 + v;
            float iv  = sigf(acc[fr][0][v] + b0_);
            float ov  = sigf(acc[fr][1][v] + b1_);
            float uv  = fmaxf(acc[fr][2][v] + b2_, 0.f);
            float f1v = sigf(acc[fr][3][v] + b3_);
            float f2v = sigf(acc[fr][4][v] + b4_);
            const ushort_t* cl = C2in + (size_t)(2 * row) * 256;
            float lC = bf16_f32(cl[j])       + bf16_f32(cl[128 + j]);
            float rC = bf16_f32(cl[256 + j]) + bf16_f32(cl[384 + j]);
            float c_ = fmaf(iv, uv, fmaf(f1v, lC, f2v * rC));
            float h_ = ov * fmaxf(c_, 0.f);
            unsigned short chi = bf16_rne(c_);
            unsigned short clo = bf16_rne(c_ - bf16_f32(chi));
            unsigned short hhi = bf16_rne(h_);
            unsigned short hlo = bf16_rne(h_ - bf16_f32(hhi));
            C2out[(size_t)row * 256 + j]       = chi;
            C2out[(size_t)row * 256 + 128 + j] = clo;
            H2out[(size_t)row * 256 + j]       = hhi;
            H2out[(size_t)row * 256 + 128 + j] = hlo;
        }
}

// ---------------------------------------------------------------------------
// Tiny level (m <= 4096): 1 wave per block; grid (ceil(m/16), 8),
// cb = blockIdx.y. Proven ~4.3 µs/launch. (unchanged)
// ---------------------------------------------------------------------------
__global__ __launch_bounds__(64)
void level_tiny(const ushort_t* __restrict__ H2in, const ushort_t* __restrict__ C2in,
                const ushort_t* __restrict__ WtPL,
                const float* __restrict__ bUi, const float* __restrict__ bUo,
                const float* __restrict__ bUu, const float* __restrict__ bf1,
                const float* __restrict__ bf2,
                ushort_t* __restrict__ H2out, ushort_t* __restrict__ C2out, int n)
{
    const int lane = threadIdx.x;
    const int l15 = lane & 15, l4 = lane >> 4;
    const int cb = blockIdx.y;
    const int rb = blockIdx.x * 16;
    const ushort_t* slab = WtPL + (size_t)cb * 32768;

    int prow = rb + l15; if (prow > n - 1) prow = n - 1;
    const ushort_t* r0 = H2in + (size_t)(2 * prow) * 256;

    f32x4 acc[5];
#pragma unroll
    for (int g = 0; g < 5; ++g) acc[g] = (f32x4){0.f, 0.f, 0.f, 0.f};

#pragma unroll
    for (int cc = 0; cc < 8; ++cc) {
        const int csel = cc >> 2;
        const int aoff = csel * 256 + (cc & 3) * 32 + l4 * 8;
        short8v Ah = *(const short8v*)(r0 + aoff);
        short8v Al = *(const short8v*)(r0 + aoff + 128);
#pragma unroll
        for (int s = 0; s < 4; ++s) {
            const int col = (s < 3) ? s : 3 + csel;
            short8v Bh = *(const short8v*)(slab + (size_t)(cc * 4 + s) * 512 + lane * 8);
            short8v Bw = *(const short8v*)(slab + (size_t)((cc + 8) * 4 + s) * 512 + lane * 8);
            acc[col] = __builtin_amdgcn_mfma_f32_16x16x32_bf16(Ah, Bh, acc[col], 0, 0, 0);
            acc[col] = __builtin_amdgcn_mfma_f32_16x16x32_bf16(Al, Bh, acc[col], 0, 0, 0);
            acc[col] = __builtin_amdgcn_mfma_f32_16x16x32_bf16(Ah, Bw, acc[col], 0, 0, 0);
        }
    }

    const int j = cb * 16 + l15;
    const float b0_ = bUi[j], b1_ = bUo[j], b2_ = bUu[j], b3_ = bf1[j], b4_ = bf2[j];
#pragma unroll
    for (int v = 0; v < 4; ++v) {
        const int row = rb + l4 * 4 + v;
        if (row < n) {
            float iv  = sigf(acc[0][v] + b0_);
            float ov  = sigf(acc[1][v] + b1_);
            float uv  = fmaxf(acc[2][v] + b2_, 0.f);
            float f1v = sigf(acc[3][v] + b3_);
            float f2v = sigf(acc[4][v] + b4_);
            const ushort_t* cl = C2in + (size_t)(2 * row) * 256;
            float lC = bf16_f32(cl[j])       + bf16_f32(cl[128 + j]);
            float rC = bf16_f32(cl[256 + j]) + bf16_f32(cl[384 + j]);
            float c_ = fmaf(iv, uv, fmaf(f1v, lC, f2v * rC));
            float h_ = ov * fmaxf(c_, 0.f);
            unsigned short chi = bf16_rne(c_);
            unsigned short clo = bf16_rne(c_ - bf16_f32(chi));
            unsigned short hhi = bf16_rne(h_);
            unsigned short hlo = bf16_rne(h_ - bf16_f32(hhi));
            C2out[(size_t)row * 256 + j]       = chi;
            C2out[(size_t)row * 256 + 128 + j] = clo;
            H2out[(size_t)row * 256 + j]       = hhi;
            H2out[(size_t)row * 256 + 128 + j] = hlo;
        }
    }
}

// ---------------------------------------------------------------------------
// Projection: 4 rows per wave, P cached in registers. (unchanged)
// ---------------------------------------------------------------------------
__global__ __launch_bounds__(256)
void proj4(const ushort_t* __restrict__ H2, const float* __restrict__ P,
           const float* __restrict__ bP, float* __restrict__ out, int total)
{
    const int w = blockIdx.x * 4 + (threadIdx.x >> 6);
    const int lane = threadIdx.x & 63;
    const int k0 = 2 * lane, k1 = 2 * lane + 1;
    float p0[NCLS], p1[NCLS];
#pragma unroll
    for (int c = 0; c < NCLS; ++c) { p0[c] = P[k0 * NCLS + c]; p1[c] = P[k1 * NCLS + c]; }

    for (int rr = 0; rr < 4; ++rr) {
        const int row = w * 4 + rr;
        if (row >= total) return;
        const unsigned* hr = (const unsigned*)(H2 + (size_t)row * 256);
        unsigned uh = hr[lane];
        unsigned ul = hr[64 + lane];
        float h0 = bf16_f32((unsigned short)(uh & 0xffffu)) + bf16_f32((unsigned short)(ul & 0xffffu));
        float h1 = bf16_f32((unsigned short)(uh >> 16)) + bf16_f32((unsigned short)(ul >> 16));
        float a[NCLS];
#pragma unroll
        for (int c = 0; c < NCLS; ++c)
            a[c] = fmaf(h0, p0[c], h1 * p1[c]);
        for (int off = 32; off; off >>= 1)
#pragma unroll
            for (int c = 0; c < NCLS; ++c) a[c] += __shfl_down(a[c], off, 64);
        if (lane == 0)
#pragma unroll
            for (int c = 0; c < NCLS; ++c) out[(size_t)row * NCLS + c] = a[c] + bP[c];
    }
}

// ---------------------------------------------------------------------------
// Host launcher.
// ws: WtPL@0 (512K) | WtPF@524288 (192K) | H2@1048576 (67.11M) | C2@68157440
// (67.11M) — ends ~135.3 MB. Node rows write-once; offsets: leaf@0,
// 32768@65536, 16384@98304, 8192@114688, then tiny levels 4096..1 appended.
// ---------------------------------------------------------------------------
extern "C" void kernel_launch(void* const* d_in, const int* in_sizes, int n_in,
                              void* d_out, int out_size, void* d_ws, size_t ws_size,
                              hipStream_t stream)
{
    const int*   words = (const int*)  d_in[0];
    const float* emb   = (const float*)d_in[1];
    const float* Wi  = (const float*)d_in[2];  const float* bi  = (const float*)d_in[3];
    const float* Wo  = (const float*)d_in[4];  const float* bo  = (const float*)d_in[5];
    const float* Wu  = (const float*)d_in[6];  const float* bu  = (const float*)d_in[7];
    const float* Ui  = (const float*)d_in[8];  const float* bUi = (const float*)d_in[9];
    const float* Uo  = (const float*)d_in[10]; const float* bUo = (const float*)d_in[11];
    const float* Uu  = (const float*)d_in[12]; const float* bUu = (const float*)d_in[13];
    const float* Uf1 = (const float*)d_in[14]; const float* bf1 = (const float*)d_in[15];
    const float* Uf2 = (const float*)d_in[16]; const float* bf2 = (const float*)d_in[17];
    const float* Pm  = (const float*)d_in[18]; const float* bP  = (const float*)d_in[19];
    float* out = (float*)d_out;

    ushort_t* WtPL = (ushort_t*)d_ws;
    ushort_t* WtPF = (ushort_t*)((char*)d_ws + 524288);
    ushort_t* H2   = (ushort_t*)((char*)d_ws + 1048576);
    ushort_t* C2   = (ushort_t*)((char*)d_ws + 68157440);

    prep_w<<<1408, 256, 0, stream>>>(Wi, Wo, Wu, Ui, Uo, Uu, Uf1, Uf2, WtPL, WtPF);

    leaf_stream<<<2048, 512, 0, stream>>>(words, emb, WtPF, bi, bo, bu, H2, C2);

    // big levels: m = 32768, 16384, 8192 (LDS-staged A)
    int off_prev = 0, off = 65536, m = 32768;
    while (m >= 8192) {
        level_lds<<<m / 32, 512, 0, stream>>>(
            H2 + (size_t)off_prev * 256, C2 + (size_t)off_prev * 256, WtPL,
            bUi, bUo, bUu, bf1, bf2,
            H2 + (size_t)off * 256, C2 + (size_t)off * 256);
        off_prev = off; off += m; m >>= 1;
    }

    // tail: m = 4096 .. 1, one tiny launch each (proven ~4.3 µs/launch)
    while (m >= 1) {
        level_tiny<<<dim3((m + 15) / 16, 8), 64, 0, stream>>>(
            H2 + (size_t)off_prev * 256, C2 + (size_t)off_prev * 256, WtPL,
            bUi, bUo, bUu, bf1, bf2,
            H2 + (size_t)off * 256, C2 + (size_t)off * 256, m);
        off_prev = off; off += m; m >>= 1;
    }

    proj4<<<8192, 256, 0, stream>>>(H2, Pm, bP, out, 131071);
}

// Round 18
// 214.498 us; speedup vs baseline: 1.4022x; 1.1418x over previous
//
#include <hip/hip_runtime.h>
#include <cstdint>
#include <cstddef>

#define NCLS 5

typedef unsigned short ushort_t;
typedef __attribute__((ext_vector_type(8))) short short8v;   // 8 bf16 (4 VGPRs)
typedef __attribute__((ext_vector_type(4))) float f32x4;     // MFMA accumulator

__device__ __forceinline__ float sigf(float x) { return 1.0f / (1.0f + __expf(-x)); }

__device__ __forceinline__ unsigned short bf16_rne(float x) {
    unsigned u = __float_as_uint(x);
    u += 0x7FFFu + ((u >> 16) & 1u);
    return (unsigned short)(u >> 16);
}
__device__ __forceinline__ float bf16_f32(unsigned short h) {
    return __uint_as_float(((unsigned)h) << 16);
}

__device__ __forceinline__ void cvt_hilo(float4 f0, float4 f1, short8v& hi, short8v& lo) {
    float v[8] = { f0.x, f0.y, f0.z, f0.w, f1.x, f1.y, f1.z, f1.w };
#pragma unroll
    for (int e = 0; e < 8; ++e) {
        unsigned short h = bf16_rne(v[e]);
        unsigned short l = bf16_rne(v[e] - bf16_f32(h));
        hi[e] = (short)h; lo[e] = (short)l;
    }
}

// ---------------------------------------------------------------------------
// Weight prep (fragment-ordered, f1/f2 packed — verified), plus projection
// table PT[cc 8][lane 64][e 8]: col=lane&15 (cols>=5 zero), kq=(lane>>4)*8+e,
// kc=(cc&3)*32+kq; cc<4 = hi band of P[kc][col], cc>=4 = lo band.
// ---------------------------------------------------------------------------
__global__ __launch_bounds__(256)
void prep_w(const float* __restrict__ Wi, const float* __restrict__ Wo,
            const float* __restrict__ Wu,
            const float* __restrict__ Ui, const float* __restrict__ Uo,
            const float* __restrict__ Uu, const float* __restrict__ Uf1,
            const float* __restrict__ Uf2, const float* __restrict__ P,
            ushort_t* __restrict__ WtPL, ushort_t* __restrict__ WtPF,
            ushort_t* __restrict__ PT)
{
    int b = blockIdx.x;
    if (b < 1024) {
        int idx = b * 256 + threadIdx.x;              // 262144
        int e = idx & 7, lane = (idx >> 3) & 63;
        int slot = (idx >> 9) & 3, cc = (idx >> 11) & 15, cb = idx >> 15;
        int j  = cb * 16 + (lane & 15);
        int kq = (lane >> 4) * 8 + e;
        int band = cc >> 3, c8 = cc & 7, csel = c8 >> 2;
        int kc = (c8 & 3) * 32 + kq;                  // [0,128)
        float x;
        if      (slot == 0) x = Ui[(csel * 128 + kc) * 128 + j];
        else if (slot == 1) x = Uo[(csel * 128 + kc) * 128 + j];
        else if (slot == 2) x = Uu[(csel * 128 + kc) * 128 + j];
        else                x = csel ? Uf2[kc * 128 + j] : Uf1[kc * 128 + j];
        unsigned short h = bf16_rne(x);
        if (band) h = bf16_rne(x - bf16_f32(h));
        WtPL[idx] = h;
    } else if (b < 1408) {
        int idx = (b - 1024) * 256 + threadIdx.x;     // 98304
        if (idx >= 98304) return;
        int e = idx & 7, lane = (idx >> 3) & 63;
        int rest = idx >> 9;
        int slot = rest % 3, cc = (rest / 3) & 7, cb = rest / 24;
        int j  = cb * 16 + (lane & 15);
        int kq = (lane >> 4) * 8 + e;
        int band = cc >> 2;
        int kc = (cc & 3) * 32 + kq;                  // [0,128)
        const float* W = (slot == 0) ? Wi : (slot == 1) ? Wo : Wu;
        float x = W[kc * 128 + j];
        unsigned short h = bf16_rne(x);
        if (band) h = bf16_rne(x - bf16_f32(h));
        WtPF[idx] = h;
    } else {
        int idx = (b - 1408) * 256 + threadIdx.x;     // 4096
        if (idx >= 4096) return;
        int e = idx & 7, lane = (idx >> 3) & 63, cc = idx >> 9;
        int col = lane & 15;
        int kq  = (lane >> 4) * 8 + e;
        int band = cc >> 2;
        int kc = (cc & 3) * 32 + kq;                  // [0,128)
        float x = (col < NCLS) ? P[kc * NCLS + col] : 0.f;
        unsigned short h = bf16_rne(x);
        if (band) h = bf16_rne(x - bf16_f32(h));
        PT[idx] = h;
    }
}

// ---------------------------------------------------------------------------
// Leaf: gather+convert ONCE per block into LDS (each wave does 4 rows), then
// all 8 waves read A-frags from LDS; B depth-1 prefetched. BM=32. (frozen)
// ---------------------------------------------------------------------------
__global__ __launch_bounds__(512)
void leaf_stream(const int* __restrict__ words, const float* __restrict__ emb,
                 const ushort_t* __restrict__ WtPF,
                 const float* __restrict__ bi, const float* __restrict__ bo,
                 const float* __restrict__ bu,
                 ushort_t* __restrict__ H2out, ushort_t* __restrict__ C2out)
{
    __shared__ ushort_t EA[32 * 264];                 // 16.5 KB
    const int tid = threadIdx.x, lane = tid & 63, wc = tid >> 6;
    const int l15 = lane & 15, l4 = lane >> 4;
    const int rb = blockIdx.x * 32;
    const ushort_t* slab = WtPF + (size_t)wc * 12288;

    {
        const int rl = wc * 4 + (lane >> 4);          // [0,32)
        const int g  = lane & 15;
        const float* e = emb + (size_t)words[rb + rl] * 128 + g * 8;
        float4 f0 = *(const float4*)(e);
        float4 f1 = *(const float4*)(e + 4);
        short8v hi, lo;
        cvt_hilo(f0, f1, hi, lo);
        *(short8v*)(EA + rl * 264 + g * 8)       = hi;
        *(short8v*)(EA + rl * 264 + 128 + g * 8) = lo;
    }
    __syncthreads();

    f32x4 acc[2][3];
#pragma unroll
    for (int fr = 0; fr < 2; ++fr)
#pragma unroll
        for (int g = 0; g < 3; ++g) acc[fr][g] = (f32x4){0.f, 0.f, 0.f, 0.f};

    short8v pB0, pB1, pB2, pB3, pB4, pB5;
#define LEAF_B(c) do {                                                        \
        pB0 = *(const short8v*)(slab + (size_t)((c) * 3 + 0) * 512 + lane * 8); \
        pB1 = *(const short8v*)(slab + (size_t)((c) * 3 + 1) * 512 + lane * 8); \
        pB2 = *(const short8v*)(slab + (size_t)((c) * 3 + 2) * 512 + lane * 8); \
        pB3 = *(const short8v*)(slab + (size_t)(((c) + 4) * 3 + 0) * 512 + lane * 8); \
        pB4 = *(const short8v*)(slab + (size_t)(((c) + 4) * 3 + 1) * 512 + lane * 8); \
        pB5 = *(const short8v*)(slab + (size_t)(((c) + 4) * 3 + 2) * 512 + lane * 8); \
    } while (0)

    LEAF_B(0);
#pragma unroll
    for (int cc = 0; cc < 4; ++cc) {
        short8v Bh[3] = { pB0, pB1, pB2 };
        short8v Bl[3] = { pB3, pB4, pB5 };
        if (cc < 3) LEAF_B(cc + 1);
        const int ko = cc * 32 + l4 * 8;
        short8v Ah0 = *(const short8v*)(EA + l15 * 264 + ko);
        short8v Ah1 = *(const short8v*)(EA + (16 + l15) * 264 + ko);
        short8v Al0 = *(const short8v*)(EA + l15 * 264 + 128 + ko);
        short8v Al1 = *(const short8v*)(EA + (16 + l15) * 264 + 128 + ko);
#pragma unroll
        for (int s = 0; s < 3; ++s) {
            acc[0][s] = __builtin_amdgcn_mfma_f32_16x16x32_bf16(Ah0, Bh[s], acc[0][s], 0, 0, 0);
            acc[1][s] = __builtin_amdgcn_mfma_f32_16x16x32_bf16(Ah1, Bh[s], acc[1][s], 0, 0, 0);
            acc[0][s] = __builtin_amdgcn_mfma_f32_16x16x32_bf16(Al0, Bh[s], acc[0][s], 0, 0, 0);
            acc[1][s] = __builtin_amdgcn_mfma_f32_16x16x32_bf16(Al1, Bh[s], acc[1][s], 0, 0, 0);
            acc[0][s] = __builtin_amdgcn_mfma_f32_16x16x32_bf16(Ah0, Bl[s], acc[0][s], 0, 0, 0);
            acc[1][s] = __builtin_amdgcn_mfma_f32_16x16x32_bf16(Ah1, Bl[s], acc[1][s], 0, 0, 0);
        }
    }
#undef LEAF_B

    const int j = wc * 16 + l15;
    const float bi_ = bi[j], bo_ = bo[j], bu_ = bu[j];
#pragma unroll
    for (int fr = 0; fr < 2; ++fr)
#pragma unroll
        for (int v = 0; v < 4; ++v) {
            const int row = rb + fr * 16 + l4 * 4 + v;
            float iv = sigf(acc[fr][0][v] + bi_);
            float ov = sigf(acc[fr][1][v] + bo_);
            float uv = fmaxf(acc[fr][2][v] + bu_, 0.f);
            float c_ = iv * uv;
            float h_ = ov * fmaxf(c_, 0.f);
            unsigned short chi = bf16_rne(c_);
            unsigned short clo = bf16_rne(c_ - bf16_f32(chi));
            unsigned short hhi = bf16_rne(h_);
            unsigned short hlo = bf16_rne(h_ - bf16_f32(hhi));
            C2out[(size_t)row * 256 + j]       = chi;
            C2out[(size_t)row * 256 + 128 + j] = clo;
            H2out[(size_t)row * 256 + j]       = hhi;
            H2out[(size_t)row * 256 + 128 + j] = hlo;
        }
}

// ---------------------------------------------------------------------------
// Level with LDS-staged A (m >= 8192). BM=32, 8 waves. (frozen from r17)
// ---------------------------------------------------------------------------
__global__ __launch_bounds__(512)
void level_lds(const ushort_t* __restrict__ H2in, const ushort_t* __restrict__ C2in,
               const ushort_t* __restrict__ WtPL,
               const float* __restrict__ bUi, const float* __restrict__ bUo,
               const float* __restrict__ bUu, const float* __restrict__ bf1,
               const float* __restrict__ bf2,
               ushort_t* __restrict__ H2out, ushort_t* __restrict__ C2out)
{
    __shared__ ushort_t EA[64 * 264];                 // 33.8 KB
    const int tid = threadIdx.x, lane = tid & 63, wc = tid >> 6;
    const int l15 = lane & 15, l4 = lane >> 4;
    const int rb = blockIdx.x * 32;
    const ushort_t* slab = WtPL + (size_t)wc * 32768;

    {
        const ushort_t* src = H2in + (size_t)(2 * rb) * 256;
        const int cr  = tid >> 3;                     // [0,64) child row
        const int seg = tid & 7;                      // 64B segment
#pragma unroll
        for (int i = 0; i < 4; ++i) {
            short8v v = *(const short8v*)(src + cr * 256 + seg * 32 + i * 8);
            *(short8v*)(EA + cr * 264 + seg * 32 + i * 8) = v;
        }
    }
    __syncthreads();

    f32x4 acc[2][5];
#pragma unroll
    for (int fr = 0; fr < 2; ++fr)
#pragma unroll
        for (int g = 0; g < 5; ++g) acc[fr][g] = (f32x4){0.f, 0.f, 0.f, 0.f};

#pragma unroll
    for (int cc = 0; cc < 8; ++cc) {
        const int csel = cc >> 2;
        const int ko = (cc & 3) * 32 + l4 * 8;
        short8v Ah0 = *(const short8v*)(EA + (2 * l15 + csel) * 264 + ko);
        short8v Ah1 = *(const short8v*)(EA + (2 * (16 + l15) + csel) * 264 + ko);
        short8v Al0 = *(const short8v*)(EA + (2 * l15 + csel) * 264 + 128 + ko);
        short8v Al1 = *(const short8v*)(EA + (2 * (16 + l15) + csel) * 264 + 128 + ko);
        short8v Bh[4], Bw[4];
#pragma unroll
        for (int s = 0; s < 4; ++s) {
            Bh[s] = *(const short8v*)(slab + (size_t)(cc * 4 + s) * 512 + lane * 8);
            Bw[s] = *(const short8v*)(slab + (size_t)((cc + 8) * 4 + s) * 512 + lane * 8);
        }
#pragma unroll
        for (int s = 0; s < 4; ++s) {
            const int col = (s < 3) ? s : 3 + csel;
            acc[0][col] = __builtin_amdgcn_mfma_f32_16x16x32_bf16(Ah0, Bh[s], acc[0][col], 0, 0, 0);
            acc[1][col] = __builtin_amdgcn_mfma_f32_16x16x32_bf16(Ah1, Bh[s], acc[1][col], 0, 0, 0);
            acc[0][col] = __builtin_amdgcn_mfma_f32_16x16x32_bf16(Al0, Bh[s], acc[0][col], 0, 0, 0);
            acc[1][col] = __builtin_amdgcn_mfma_f32_16x16x32_bf16(Al1, Bh[s], acc[1][col], 0, 0, 0);
            acc[0][col] = __builtin_amdgcn_mfma_f32_16x16x32_bf16(Ah0, Bw[s], acc[0][col], 0, 0, 0);
            acc[1][col] = __builtin_amdgcn_mfma_f32_16x16x32_bf16(Ah1, Bw[s], acc[1][col], 0, 0, 0);
        }
    }

    const int j = wc * 16 + l15;
    const float b0_ = bUi[j], b1_ = bUo[j], b2_ = bUu[j], b3_ = bf1[j], b4_ = bf2[j];
#pragma unroll
    for (int fr = 0; fr < 2; ++fr)
#pragma unroll
        for (int v = 0; v < 4; ++v) {
            const int row = rb + fr * 16 + l4 * 4 + v;
            float iv  = sigf(acc[fr][0][v] + b0_);
            float ov  = sigf(acc[fr][1][v] + b1_);
            float uv  = fmaxf(acc[fr][2][v] + b2_, 0.f);
            float f1v = sigf(acc[fr][3][v] + b3_);
            float f2v = sigf(acc[fr][4][v] + b4_);
            const ushort_t* cl = C2in + (size_t)(2 * row) * 256;
            float lC = bf16_f32(cl[j])       + bf16_f32(cl[128 + j]);
            float rC = bf16_f32(cl[256 + j]) + bf16_f32(cl[384 + j]);
            float c_ = fmaf(iv, uv, fmaf(f1v, lC, f2v * rC));
            float h_ = ov * fmaxf(c_, 0.f);
            unsigned short chi = bf16_rne(c_);
            unsigned short clo = bf16_rne(c_ - bf16_f32(chi));
            unsigned short hhi = bf16_rne(h_);
            unsigned short hlo = bf16_rne(h_ - bf16_f32(hhi));
            C2out[(size_t)row * 256 + j]       = chi;
            C2out[(size_t)row * 256 + 128 + j] = clo;
            H2out[(size_t)row * 256 + j]       = hhi;
            H2out[(size_t)row * 256 + 128 + j] = hlo;
        }
}

// ---------------------------------------------------------------------------
// Tiny level (m <= 4096): 1 wave per block; grid (ceil(m/16), 8),
// cb = blockIdx.y. Proven ~4.3 µs/launch. (frozen)
// ---------------------------------------------------------------------------
__global__ __launch_bounds__(64)
void level_tiny(const ushort_t* __restrict__ H2in, const ushort_t* __restrict__ C2in,
                const ushort_t* __restrict__ WtPL,
                const float* __restrict__ bUi, const float* __restrict__ bUo,
                const float* __restrict__ bUu, const float* __restrict__ bf1,
                const float* __restrict__ bf2,
                ushort_t* __restrict__ H2out, ushort_t* __restrict__ C2out, int n)
{
    const int lane = threadIdx.x;
    const int l15 = lane & 15, l4 = lane >> 4;
    const int cb = blockIdx.y;
    const int rb = blockIdx.x * 16;
    const ushort_t* slab = WtPL + (size_t)cb * 32768;

    int prow = rb + l15; if (prow > n - 1) prow = n - 1;
    const ushort_t* r0 = H2in + (size_t)(2 * prow) * 256;

    f32x4 acc[5];
#pragma unroll
    for (int g = 0; g < 5; ++g) acc[g] = (f32x4){0.f, 0.f, 0.f, 0.f};

#pragma unroll
    for (int cc = 0; cc < 8; ++cc) {
        const int csel = cc >> 2;
        const int aoff = csel * 256 + (cc & 3) * 32 + l4 * 8;
        short8v Ah = *(const short8v*)(r0 + aoff);
        short8v Al = *(const short8v*)(r0 + aoff + 128);
#pragma unroll
        for (int s = 0; s < 4; ++s) {
            const int col = (s < 3) ? s : 3 + csel;
            short8v Bh = *(const short8v*)(slab + (size_t)(cc * 4 + s) * 512 + lane * 8);
            short8v Bw = *(const short8v*)(slab + (size_t)((cc + 8) * 4 + s) * 512 + lane * 8);
            acc[col] = __builtin_amdgcn_mfma_f32_16x16x32_bf16(Ah, Bh, acc[col], 0, 0, 0);
            acc[col] = __builtin_amdgcn_mfma_f32_16x16x32_bf16(Al, Bh, acc[col], 0, 0, 0);
            acc[col] = __builtin_amdgcn_mfma_f32_16x16x32_bf16(Ah, Bw, acc[col], 0, 0, 0);
        }
    }

    const int j = cb * 16 + l15;
    const float b0_ = bUi[j], b1_ = bUo[j], b2_ = bUu[j], b3_ = bf1[j], b4_ = bf2[j];
#pragma unroll
    for (int v = 0; v < 4; ++v) {
        const int row = rb + l4 * 4 + v;
        if (row < n) {
            float iv  = sigf(acc[0][v] + b0_);
            float ov  = sigf(acc[1][v] + b1_);
            float uv  = fmaxf(acc[2][v] + b2_, 0.f);
            float f1v = sigf(acc[3][v] + b3_);
            float f2v = sigf(acc[4][v] + b4_);
            const ushort_t* cl = C2in + (size_t)(2 * row) * 256;
            float lC = bf16_f32(cl[j])       + bf16_f32(cl[128 + j]);
            float rC = bf16_f32(cl[256 + j]) + bf16_f32(cl[384 + j]);
            float c_ = fmaf(iv, uv, fmaf(f1v, lC, f2v * rC));
            float h_ = ov * fmaxf(c_, 0.f);
            unsigned short chi = bf16_rne(c_);
            unsigned short clo = bf16_rne(c_ - bf16_f32(chi));
            unsigned short hhi = bf16_rne(h_);
            unsigned short hlo = bf16_rne(h_ - bf16_f32(hhi));
            C2out[(size_t)row * 256 + j]       = chi;
            C2out[(size_t)row * 256 + 128 + j] = clo;
            H2out[(size_t)row * 256 + j]       = hhi;
            H2out[(size_t)row * 256 + 128 + j] = hlo;
        }
    }
}

// ---------------------------------------------------------------------------
// Projection as MFMA GEMM: out = H(131071x128) @ P(128x5->16), 16 rows/wave.
// 12 MFMAs per tile (Hh·Ph + Hl·Ph + Hh·Pl over 4 K-chunks).
// ---------------------------------------------------------------------------
__global__ __launch_bounds__(256)
void proj_mfma(const ushort_t* __restrict__ H2, const ushort_t* __restrict__ PT,
               const float* __restrict__ bP, float* __restrict__ out, int total)
{
    const int tid = threadIdx.x, lane = tid & 63, w = tid >> 6;
    const int l15 = lane & 15, l4 = lane >> 4;
    const int rb = (blockIdx.x * 4 + w) * 16;

    int ar = rb + l15; if (ar > total - 1) ar = total - 1;
    const ushort_t* hr = H2 + (size_t)ar * 256;

    f32x4 acc = (f32x4){0.f, 0.f, 0.f, 0.f};
#pragma unroll
    for (int cc = 0; cc < 4; ++cc) {
        const int ko = cc * 32 + l4 * 8;
        short8v Ah = *(const short8v*)(hr + ko);
        short8v Al = *(const short8v*)(hr + 128 + ko);
        short8v Bh = *(const short8v*)(PT + ((size_t)(cc * 64) + lane) * 8);
        short8v Bl = *(const short8v*)(PT + ((size_t)((cc + 4) * 64) + lane) * 8);
        acc = __builtin_amdgcn_mfma_f32_16x16x32_bf16(Ah, Bh, acc, 0, 0, 0);
        acc = __builtin_amdgcn_mfma_f32_16x16x32_bf16(Al, Bh, acc, 0, 0, 0);
        acc = __builtin_amdgcn_mfma_f32_16x16x32_bf16(Ah, Bl, acc, 0, 0, 0);
    }

    if (l15 < NCLS) {
        const float b = bP[l15];
#pragma unroll
        for (int v = 0; v < 4; ++v) {
            const int row = rb + l4 * 4 + v;
            if (row < total)
                out[(size_t)row * NCLS + l15] = acc[v] + b;
        }
    }
}

// ---------------------------------------------------------------------------
// Host launcher.
// ws: WtPL@0 (512K) | WtPF@524288 (192K) | PT@720896 (8K) | H2@1048576
// (67.11M) | C2@68157440 (67.11M) — ends ~135.3 MB. Node rows write-once;
// offsets: leaf@0, 32768@65536, 16384@98304, 8192@114688, tiny 4096..1 after.
// ---------------------------------------------------------------------------
extern "C" void kernel_launch(void* const* d_in, const int* in_sizes, int n_in,
                              void* d_out, int out_size, void* d_ws, size_t ws_size,
                              hipStream_t stream)
{
    const int*   words = (const int*)  d_in[0];
    const float* emb   = (const float*)d_in[1];
    const float* Wi  = (const float*)d_in[2];  const float* bi  = (const float*)d_in[3];
    const float* Wo  = (const float*)d_in[4];  const float* bo  = (const float*)d_in[5];
    const float* Wu  = (const float*)d_in[6];  const float* bu  = (const float*)d_in[7];
    const float* Ui  = (const float*)d_in[8];  const float* bUi = (const float*)d_in[9];
    const float* Uo  = (const float*)d_in[10]; const float* bUo = (const float*)d_in[11];
    const float* Uu  = (const float*)d_in[12]; const float* bUu = (const float*)d_in[13];
    const float* Uf1 = (const float*)d_in[14]; const float* bf1 = (const float*)d_in[15];
    const float* Uf2 = (const float*)d_in[16]; const float* bf2 = (const float*)d_in[17];
    const float* Pm  = (const float*)d_in[18]; const float* bP  = (const float*)d_in[19];
    float* out = (float*)d_out;

    ushort_t* WtPL = (ushort_t*)d_ws;
    ushort_t* WtPF = (ushort_t*)((char*)d_ws + 524288);
    ushort_t* PT   = (ushort_t*)((char*)d_ws + 720896);
    ushort_t* H2   = (ushort_t*)((char*)d_ws + 1048576);
    ushort_t* C2   = (ushort_t*)((char*)d_ws + 68157440);

    prep_w<<<1424, 256, 0, stream>>>(Wi, Wo, Wu, Ui, Uo, Uu, Uf1, Uf2, Pm,
                                     WtPL, WtPF, PT);

    leaf_stream<<<2048, 512, 0, stream>>>(words, emb, WtPF, bi, bo, bu, H2, C2);

    // big levels: m = 32768, 16384, 8192 (LDS-staged A)
    int off_prev = 0, off = 65536, m = 32768;
    while (m >= 8192) {
        level_lds<<<m / 32, 512, 0, stream>>>(
            H2 + (size_t)off_prev * 256, C2 + (size_t)off_prev * 256, WtPL,
            bUi, bUo, bUu, bf1, bf2,
            H2 + (size_t)off * 256, C2 + (size_t)off * 256);
        off_prev = off; off += m; m >>= 1;
    }

    // tail: m = 4096 .. 1, one tiny launch each (proven ~4.3 µs/launch)
    while (m >= 1) {
        level_tiny<<<dim3((m + 15) / 16, 8), 64, 0, stream>>>(
            H2 + (size_t)off_prev * 256, C2 + (size_t)off_prev * 256, WtPL,
            bUi, bUo, bUu, bf1, bf2,
            H2 + (size_t)off * 256, C2 + (size_t)off * 256, m);
        off_prev = off; off += m; m >>= 1;
    }

    proj_mfma<<<2048, 256, 0, stream>>>(H2, PT, bP, out, 131071);
}